// Round 1
// baseline (70.364 us; speedup 1.0000x reference)
//
#include <hip/hip_runtime.h>

#define RADIUS2 0.01f
#define NS 32
#define B_ 4
#define M_ 2048
#define N_ 8192
#define C_ 64
#define OUTW 67            // 3 + C
#define PERQ (NS * OUTW)   // 2144

__global__ __launch_bounds__(256) void ballquery_group_kernel(
    const float* __restrict__ new_xyz,   // [B, M, 3]
    const float* __restrict__ pointset,  // [B, N, 3]
    const float* __restrict__ feature,   // [B, N, C]
    float* __restrict__ out)             // [B, M, NS, 67]
{
    const int w    = threadIdx.x >> 6;   // wave in block (0..3)
    const int lane = threadIdx.x & 63;
    const int q    = blockIdx.x * 4 + w; // global query id, 0..B*M-1
    const int b    = q >> 11;            // q / M  (M = 2048)

    __shared__ int sidx[4][NS];

    const float qx = new_xyz[q * 3 + 0];
    const float qy = new_xyz[q * 3 + 1];
    const float qz = new_xyz[q * 3 + 2];

    const float* __restrict__ ps = pointset + (size_t)b * N_ * 3;

    // ---- phase 1: ball query (first NS points with d2 < r2, ascending index) ----
    int cnt = 0;
    for (int c = 0; c < N_ / 64 && cnt < NS; ++c) {
        const int i = c * 64 + lane;
        const float px = ps[i * 3 + 0];
        const float py = ps[i * 3 + 1];
        const float pz = ps[i * 3 + 2];
        const float dx = qx - px;
        const float dy = qy - py;
        const float dz = qz - pz;
        // exact non-fma sum of squares to match the reference's tie-breaking
        const float d2 = __fadd_rn(__fadd_rn(__fmul_rn(dx, dx), __fmul_rn(dy, dy)),
                                   __fmul_rn(dz, dz));
        const bool in = d2 < RADIUS2;
        const unsigned long long mk = __ballot(in);
        if (mk) {
            if (in) {
                const int slot = cnt + __popcll(mk & ((1ull << lane) - 1ull));
                if (slot < NS) sidx[w][slot] = i;
            }
            cnt += (int)__popcll(mk);
        }
    }
    if (cnt > NS) cnt = NS;
    __syncthreads();

    // pad unused slots with first found index (or 0 if none found) — CUDA semantics
    const int first = (cnt > 0) ? sidx[w][0] : 0;
    if (lane < NS && lane >= cnt) sidx[w][lane] = first;
    __syncthreads();

    // ---- phase 2: gather + concat ----
    const float* __restrict__ fb = feature + (size_t)b * N_ * C_;
    float* __restrict__ outq = out + (size_t)q * PERQ;

    int s = 0;          // sample slot 0..31
    int c = lane;       // channel 0..66
    for (int o = lane; o < PERQ; o += 64) {
        const int i = sidx[w][s];
        float v;
        if (c < 3) {
            v = ps[i * 3 + c] - new_xyz[q * 3 + c];   // local_xyz = p - q
        } else {
            v = fb[(size_t)i * C_ + (c - 3)];
        }
        outq[o] = v;
        c += 64;
        if (c >= OUTW) { c -= OUTW; s += 1; }
    }
}

extern "C" void kernel_launch(void* const* d_in, const int* in_sizes, int n_in,
                              void* d_out, int out_size, void* d_ws, size_t ws_size,
                              hipStream_t stream) {
    const float* new_xyz  = (const float*)d_in[0];
    const float* pointset = (const float*)d_in[1];
    const float* feature  = (const float*)d_in[2];
    float* out = (float*)d_out;

    const int nq = B_ * M_;               // 8192 queries
    const int blocks = nq / 4;            // 4 waves (queries) per 256-thread block
    ballquery_group_kernel<<<blocks, 256, 0, stream>>>(new_xyz, pointset, feature, out);
}

// Round 2
// 66.628 us; speedup vs baseline: 1.0561x; 1.0561x over previous
//
#include <hip/hip_runtime.h>

#define RADIUS2 0.01f
#define NS 32
#define B_ 4
#define M_ 2048
#define N_ 8192
#define C_ 64
#define OUTW 67            // 3 + C
#define PERQ (NS * OUTW)   // 2144
#define NCHUNK (N_ / 64)   // 128
#define GROUP 16           // chunks per early-exit check

__global__ __launch_bounds__(256) void ballquery_group_kernel(
    const float* __restrict__ new_xyz,   // [B, M, 3]
    const float* __restrict__ pointset,  // [B, N, 3]
    const float* __restrict__ feature,   // [B, N, C]
    float* __restrict__ out)             // [B, M, NS, 67]
{
    const int w    = threadIdx.x >> 6;   // wave in block (0..3)
    const int lane = threadIdx.x & 63;
    const int q    = blockIdx.x * 4 + w; // global query id, 0..B*M-1
    const int b    = q >> 11;            // q / M  (M = 2048)

    __shared__ int sidx[4][NS];

    const float qx = new_xyz[q * 3 + 0];
    const float qy = new_xyz[q * 3 + 1];
    const float qz = new_xyz[q * 3 + 2];

    const float* __restrict__ ps = pointset + (size_t)b * N_ * 3;

    // ---- phase 1: first NS points with d2 < r2, ascending index ----
    // Coarse early exit (every GROUP chunks): inner block fully unrolled so
    // its 3*GROUP loads pipeline without waiting on the ballot chain.
    int cnt = 0;
    for (int g = 0; g < NCHUNK / GROUP; ++g) {
        if (cnt >= NS) break;
#pragma unroll
        for (int u = 0; u < GROUP; ++u) {
            const int i = (g * GROUP + u) * 64 + lane;
            const float px = ps[i * 3 + 0];
            const float py = ps[i * 3 + 1];
            const float pz = ps[i * 3 + 2];
            const float dx = qx - px;
            const float dy = qy - py;
            const float dz = qz - pz;
            // exact non-fma sum of squares to match reference tie-breaking
            const float d2 = __fadd_rn(__fadd_rn(__fmul_rn(dx, dx), __fmul_rn(dy, dy)),
                                       __fmul_rn(dz, dz));
            const bool in = d2 < RADIUS2;
            const unsigned long long mk = __ballot(in);
            // prefix popcount below my lane (v_mbcnt_lo/hi pair)
            const unsigned pre = __builtin_amdgcn_mbcnt_hi(
                (unsigned)(mk >> 32),
                __builtin_amdgcn_mbcnt_lo((unsigned)mk, 0u));
            if (in) {
                const int slot = cnt + (int)pre;
                if (slot < NS) sidx[w][slot] = i;
            }
            cnt += (int)__popcll(mk);
        }
    }
    if (cnt > NS) cnt = NS;
    __syncthreads();

    // pad unused slots with first found index (or 0 if none) — CUDA semantics
    const int first = (cnt > 0) ? sidx[w][0] : 0;
    if (lane < NS && lane >= cnt) sidx[w][lane] = first;
    __syncthreads();

    // ---- phase 2: gather + concat ----
    const float* __restrict__ fb = feature + (size_t)b * N_ * C_;
    float* __restrict__ outq = out + (size_t)q * PERQ;

    int s = 0;          // sample slot 0..31
    int c = lane;       // channel 0..66
    for (int o = lane; o < PERQ; o += 64) {
        const int i = sidx[w][s];
        float v;
        if (c < 3) {
            v = ps[i * 3 + c] - new_xyz[q * 3 + c];   // local_xyz = p - q
        } else {
            v = fb[(size_t)i * C_ + (c - 3)];
        }
        outq[o] = v;
        c += 64;
        if (c >= OUTW) { c -= OUTW; s += 1; }
    }
}

extern "C" void kernel_launch(void* const* d_in, const int* in_sizes, int n_in,
                              void* d_out, int out_size, void* d_ws, size_t ws_size,
                              hipStream_t stream) {
    const float* new_xyz  = (const float*)d_in[0];
    const float* pointset = (const float*)d_in[1];
    const float* feature  = (const float*)d_in[2];
    float* out = (float*)d_out;

    const int nq = B_ * M_;               // 8192 queries
    const int blocks = nq / 4;            // 4 waves (queries) per 256-thread block
    ballquery_group_kernel<<<blocks, 256, 0, stream>>>(new_xyz, pointset, feature, out);
}

// Round 3
// 58.985 us; speedup vs baseline: 1.1929x; 1.1296x over previous
//
#include <hip/hip_runtime.h>

#define RADIUS2 0.01f
#define NS 32
#define B_ 4
#define M_ 2048
#define N_ 8192
#define C_ 64
#define OUTW 67            // 3 + C
#define PERQ (NS * OUTW)   // 2144
#define NW 8               // waves (= queries) per block
#define TILE 1024          // points per LDS tile
#define NTILE (N_ / TILE)  // 8

__global__ __launch_bounds__(NW * 64) void ballquery_group_kernel(
    const float* __restrict__ new_xyz,   // [B, M, 3]
    const float* __restrict__ pointset,  // [B, N, 3]
    const float* __restrict__ feature,   // [B, N, C]
    float* __restrict__ out)             // [B, M, NS, 67]
{
    const int tid  = threadIdx.x;
    const int w    = tid >> 6;           // wave in block (0..NW-1)
    const int lane = tid & 63;
    const int q    = blockIdx.x * NW + w;
    const int b    = q >> 11;            // q / M (M = 2048)

    __shared__ float4 spts[TILE];        // padded points (x,y,z,unused)
    __shared__ int    sidx[NW][NS];
    __shared__ int    s_done;

    const float qx = new_xyz[q * 3 + 0];
    const float qy = new_xyz[q * 3 + 1];
    const float qz = new_xyz[q * 3 + 2];

    const float* __restrict__ ps = pointset + (size_t)b * N_ * 3;

    if (tid == 0) s_done = 0;

    int  cnt     = 0;
    bool counted = false;

    for (int t = 0; t < NTILE; ++t) {
        __syncthreads();                 // prev tile's readers done; s_done visible
        if (s_done == NW) break;         // wave-uniform block early exit

        // ---- stage TILE points, padded to float4, coalesced dword reads ----
        {
            const float* __restrict__ tp = ps + t * TILE * 3;
            float* __restrict__ sp = (float*)spts;
            for (int d = tid; d < TILE * 3; d += NW * 64) {
                const int p = d / 3, c = d - p * 3;
                sp[p * 4 + c] = tp[d];
            }
        }
        __syncthreads();

        // ---- scan tile from LDS (ds_read_b128 per point) ----
        if (cnt < NS) {
#pragma unroll 4
            for (int it = 0; it < TILE / 64; ++it) {
                const float4 p = spts[it * 64 + lane];
                const float dx = qx - p.x;
                const float dy = qy - p.y;
                const float dz = qz - p.z;
                // exact non-fma sum of squares (matches reference tie-breaking)
                const float d2 = __fadd_rn(__fadd_rn(__fmul_rn(dx, dx), __fmul_rn(dy, dy)),
                                           __fmul_rn(dz, dz));
                const bool in = d2 < RADIUS2;
                const unsigned long long mk = __ballot(in);
                const unsigned pre = __builtin_amdgcn_mbcnt_hi(
                    (unsigned)(mk >> 32),
                    __builtin_amdgcn_mbcnt_lo((unsigned)mk, 0u));
                if (in) {
                    const int slot = cnt + (int)pre;
                    if (slot < NS) sidx[w][slot] = t * TILE + it * 64 + lane;
                }
                cnt += (int)__popcll(mk);
            }
        }
        if (!counted && cnt >= NS) {
            counted = true;
            if (lane == 0) atomicAdd(&s_done, 1);
        }
    }
    if (cnt > NS) cnt = NS;

    // pad unused slots with first found index (or 0 if none) — CUDA semantics.
    // sidx[w] is touched only by this wave: same-wave LDS ordering suffices.
    const int first = (cnt > 0) ? sidx[w][0] : 0;
    if (lane < NS && lane >= cnt) sidx[w][lane] = first;

    // ---- gather + concat ----
    const float* __restrict__ fb = feature + (size_t)b * N_ * C_;
    float* __restrict__ outq = out + (size_t)q * PERQ;

    int s = 0;          // sample slot 0..31
    int c = lane;       // channel 0..66
    for (int o = lane; o < PERQ; o += 64) {
        const int i = sidx[w][s];
        float v;
        if (c < 3) {
            v = ps[i * 3 + c] - new_xyz[q * 3 + c];   // local_xyz = p - q
        } else {
            v = fb[(size_t)i * C_ + (c - 3)];
        }
        outq[o] = v;
        c += 64;
        if (c >= OUTW) { c -= OUTW; s += 1; }
    }
}

extern "C" void kernel_launch(void* const* d_in, const int* in_sizes, int n_in,
                              void* d_out, int out_size, void* d_ws, size_t ws_size,
                              hipStream_t stream) {
    const float* new_xyz  = (const float*)d_in[0];
    const float* pointset = (const float*)d_in[1];
    const float* feature  = (const float*)d_in[2];
    float* out = (float*)d_out;

    const int nq = B_ * M_;               // 8192 queries
    const int blocks = nq / NW;           // 8 queries per 512-thread block
    ballquery_group_kernel<<<blocks, NW * 64, 0, stream>>>(new_xyz, pointset, feature, out);
}